// Round 3
// baseline (2151.391 us; speedup 1.0000x reference)
//
#include <hip/hip_runtime.h>
#include <hip/hip_bf16.h>

#define N_NODES   100000
#define N_EDGES   300000
#define NUM_GRAPHS 128
#define HID       256
#define SEMK      1536
#define MAX_CHILD 200

using bf16x8 = __attribute__((ext_vector_type(8))) short;
using f32x4  = __attribute__((ext_vector_type(4))) float;

__device__ __forceinline__ unsigned short f2b(float x) {
    __hip_bfloat16 h = __float2bfloat16(x);
    return __builtin_bit_cast(unsigned short, h);
}
__device__ __forceinline__ float b2f(unsigned short u) {
    __hip_bfloat16 h = __builtin_bit_cast(__hip_bfloat16, u);
    return __bfloat162float(h);
}
__device__ __forceinline__ int imin(int a, int b) { return a < b ? a : b; }
__device__ __forceinline__ int imax(int a, int b) { return a > b ? a : b; }

// ---------------- weight transpose + bf16 convert: dst[n][k] = bf16(src[k][n]), N fixed 256
__global__ __launch_bounds__(256) void transpose_bf16_kernel(
    const float* __restrict__ src, unsigned short* __restrict__ dst, int K)
{
    int idx = blockIdx.x * 256 + threadIdx.x;
    if (idx < K * 256) {
        int k = idx >> 8;
        int n = idx & 255;
        dst[n * K + k] = f2b(src[idx]);
    }
}

// ---------------- h0 = x_sem @ sem_W + sem_b + label_emb[x0] + type_emb[x1]  (bf16 out)
// block = 256 thr (4 waves), wave = 32 rows x 256 cols, block = 128 rows
__global__ __launch_bounds__(256) void node_embed_kernel(
    const float* __restrict__ x_sem, const unsigned short* __restrict__ semWt,
    const float* __restrict__ sem_b, const float* __restrict__ label_emb,
    const float* __restrict__ type_emb, const int* __restrict__ x,
    unsigned short* __restrict__ h0)
{
    const int tid = threadIdx.x;
    const int l = tid & 63, w = tid >> 6;
    const int lr = l & 15, lg = l >> 4;
    const int row0 = blockIdx.x * 128 + w * 32;

    f32x4 acc[2][16];
#pragma unroll
    for (int i = 0; i < 2; ++i)
#pragma unroll
        for (int j = 0; j < 16; ++j) acc[i][j] = f32x4{0.f, 0.f, 0.f, 0.f};

    const long a0off = (long)imin(row0 + lr, N_NODES - 1) * SEMK;
    const long a1off = (long)imin(row0 + 16 + lr, N_NODES - 1) * SEMK;

    for (int ks = 0; ks < SEMK / 32; ++ks) {
        const int k0 = ks * 32 + lg * 8;
        const float* p0 = x_sem + a0off + k0;
        const float* p1 = x_sem + a1off + k0;
        f32x4 f0a = *(const f32x4*)(p0);
        f32x4 f0b = *(const f32x4*)(p0 + 4);
        f32x4 f1a = *(const f32x4*)(p1);
        f32x4 f1b = *(const f32x4*)(p1 + 4);
        bf16x8 a0, a1;
#pragma unroll
        for (int j = 0; j < 4; ++j) {
            a0[j]     = (short)f2b(f0a[j]);
            a0[j + 4] = (short)f2b(f0b[j]);
            a1[j]     = (short)f2b(f1a[j]);
            a1[j + 4] = (short)f2b(f1b[j]);
        }
        const unsigned short* bbase = semWt + (long)lr * SEMK + k0;
#pragma unroll
        for (int ni = 0; ni < 16; ++ni) {
            bf16x8 b = *(const bf16x8*)(bbase + (long)ni * 16 * SEMK);
            acc[0][ni] = __builtin_amdgcn_mfma_f32_16x16x32_bf16(a0, b, acc[0][ni], 0, 0, 0);
            acc[1][ni] = __builtin_amdgcn_mfma_f32_16x16x32_bf16(a1, b, acc[1][ni], 0, 0, 0);
        }
    }

    // epilogue: C/D layout col = lane&15, row = (lane>>4)*4 + reg
#pragma unroll
    for (int mi = 0; mi < 2; ++mi) {
#pragma unroll
        for (int reg = 0; reg < 4; ++reg) {
            int row = row0 + mi * 16 + lg * 4 + reg;
            if (row >= N_NODES) continue;
            int li = x[row * 2 + 0];
            int ti = x[row * 2 + 1];
            const float* lrow = label_emb + (long)li * HID;
            const float* trow = type_emb + (long)ti * HID;
#pragma unroll
            for (int ni = 0; ni < 16; ++ni) {
                int col = ni * 16 + lr;
                float v = acc[mi][ni][reg] + sem_b[col] + lrow[col] + trow[col];
                h0[(long)row * HID + col] = f2b(v);
            }
        }
    }
}

// ---------------- CSR build
__global__ __launch_bounds__(256) void hist_kernel(const int* __restrict__ ei, int* __restrict__ deg)
{
    int e = blockIdx.x * 256 + threadIdx.x;
    if (e < N_EDGES) atomicAdd(&deg[ei[N_EDGES + e]], 1);
}

__global__ __launch_bounds__(1024) void scan_kernel(const int* __restrict__ deg,
    int* __restrict__ row_start, int* __restrict__ cursor, int n)
{
    __shared__ int wsum[16];
    __shared__ int woff[16];
    __shared__ int running;
    __shared__ int chunk_total;
    const int t = threadIdx.x;
    const int lane = t & 63;
    const int wv = t >> 6;
    if (t == 0) running = 0;
    __syncthreads();
    for (int base = 0; base < n; base += 1024) {
        int i = base + t;
        int v = (i < n) ? deg[i] : 0;
        int s = v;
#pragma unroll
        for (int off = 1; off < 64; off <<= 1) {
            int u = __shfl_up(s, off);
            if (lane >= off) s += u;
        }
        if (lane == 63) wsum[wv] = s;
        __syncthreads();
        if (t == 0) {
            int a = 0;
            for (int k = 0; k < 16; ++k) { woff[k] = a; a += wsum[k]; }
            chunk_total = a;
        }
        __syncthreads();
        int incl = s + woff[wv];
        int excl = running + incl - v;
        if (i < n) { row_start[i] = excl; cursor[i] = excl; }
        __syncthreads();
        if (t == 0) running += chunk_total;
        __syncthreads();
    }
    if (t == 0) row_start[n] = running;
}

__global__ __launch_bounds__(256) void scatter_kernel(const int* __restrict__ ei,
    int* __restrict__ cursor, int* __restrict__ edge_id)
{
    int e = blockIdx.x * 256 + threadIdx.x;
    if (e < N_EDGES) {
        int d = ei[N_EDGES + e];
        int pos = atomicAdd(&cursor[d], 1);
        edge_id[pos] = e;
    }
}

// ---------------- agg[n] = sum_{e: dst=n} relu(h[src_e] + role_emb[r_e] + child_emb[c_e])
// one wave per node, lane covers 4 cols
__global__ __launch_bounds__(256) void agg_kernel(
    const unsigned short* __restrict__ h, const int* __restrict__ row_start,
    const int* __restrict__ edge_id, const int* __restrict__ ei,
    const int* __restrict__ edge_attr, const float* __restrict__ role_emb,
    const float* __restrict__ child_emb, float* __restrict__ agg)
{
    const int tid = threadIdx.x;
    const int l = tid & 63, w = tid >> 6;
    const int node = blockIdx.x * 4 + w;
    if (node >= N_NODES) return;
    const int s0 = row_start[node];
    const int s1 = row_start[node + 1];
    const int c0 = l * 4;
    f32x4 sum = f32x4{0.f, 0.f, 0.f, 0.f};
    for (int j = s0; j < s1; ++j) {
        int e = edge_id[j];
        int src = ei[e];
        int role = edge_attr[e * 2 + 0];
        int ch = imin(imax(edge_attr[e * 2 + 1], 0), MAX_CHILD - 1);
        ushort4 hb = *(const ushort4*)(h + (long)src * HID + c0);
        f32x4 re = *(const f32x4*)(role_emb + (long)role * HID + c0);
        f32x4 ce = *(const f32x4*)(child_emb + (long)ch * HID + c0);
        sum[0] += fmaxf(b2f(hb.x) + re[0] + ce[0], 0.f);
        sum[1] += fmaxf(b2f(hb.y) + re[1] + ce[1], 0.f);
        sum[2] += fmaxf(b2f(hb.z) + re[2] + ce[2], 0.f);
        sum[3] += fmaxf(b2f(hb.w) + re[3] + ce[3], 0.f);
    }
    *(f32x4*)(agg + (long)node * HID + c0) = sum;
}

// ---------------- hout = relu((h+agg) @ W1 + b1) @ W2 + b2   (bf16 out)
// block = 256 thr (4 waves), wave = 16 rows x 256 cols
__global__ __launch_bounds__(256) void mlp_kernel(
    const unsigned short* __restrict__ hin, const float* __restrict__ agg,
    const unsigned short* __restrict__ W1t, const float* __restrict__ b1,
    const unsigned short* __restrict__ W2t, const float* __restrict__ b2,
    unsigned short* __restrict__ hout)
{
    __shared__ __align__(16) unsigned short t1[4][16][264];  // stride 264: 16B aligned rows, conflict-light
    const int tid = threadIdx.x;
    const int l = tid & 63, w = tid >> 6;
    const int lr = l & 15, lg = l >> 4;
    const int row0 = blockIdx.x * 64 + w * 16;
    const long roff = (long)imin(row0 + lr, N_NODES - 1) * HID;

    f32x4 acc[16];
#pragma unroll
    for (int i = 0; i < 16; ++i) acc[i] = f32x4{0.f, 0.f, 0.f, 0.f};

#pragma unroll
    for (int ks = 0; ks < 8; ++ks) {
        const int k0 = ks * 32 + lg * 8;
        bf16x8 hb = *(const bf16x8*)(hin + roff + k0);
        f32x4 ga = *(const f32x4*)(agg + roff + k0);
        f32x4 gb = *(const f32x4*)(agg + roff + k0 + 4);
        bf16x8 a;
#pragma unroll
        for (int j = 0; j < 4; ++j) {
            a[j]     = (short)f2b(b2f((unsigned short)hb[j]) + ga[j]);
            a[j + 4] = (short)f2b(b2f((unsigned short)hb[j + 4]) + gb[j]);
        }
        const unsigned short* bbase = W1t + (long)lr * HID + k0;
#pragma unroll
        for (int ni = 0; ni < 16; ++ni) {
            bf16x8 b = *(const bf16x8*)(bbase + (long)ni * 16 * HID);
            acc[ni] = __builtin_amdgcn_mfma_f32_16x16x32_bf16(a, b, acc[ni], 0, 0, 0);
        }
    }

    // t1 = relu(acc + b1) -> LDS (bf16), laid out [row][k] for GEMM2 A-frags
#pragma unroll
    for (int ni = 0; ni < 16; ++ni) {
        int col = ni * 16 + lr;
        float bv = b1[col];
#pragma unroll
        for (int reg = 0; reg < 4; ++reg) {
            int trow = lg * 4 + reg;
            t1[w][trow][col] = f2b(fmaxf(acc[ni][reg] + bv, 0.f));
        }
    }
    __syncthreads();

    f32x4 acc2[16];
#pragma unroll
    for (int i = 0; i < 16; ++i) acc2[i] = f32x4{0.f, 0.f, 0.f, 0.f};

#pragma unroll
    for (int ks = 0; ks < 8; ++ks) {
        const int k0 = ks * 32 + lg * 8;
        bf16x8 a = *(const bf16x8*)(&t1[w][lr][k0]);
        const unsigned short* bbase = W2t + (long)lr * HID + k0;
#pragma unroll
        for (int ni = 0; ni < 16; ++ni) {
            bf16x8 b = *(const bf16x8*)(bbase + (long)ni * 16 * HID);
            acc2[ni] = __builtin_amdgcn_mfma_f32_16x16x32_bf16(a, b, acc2[ni], 0, 0, 0);
        }
    }

#pragma unroll
    for (int ni = 0; ni < 16; ++ni) {
        int col = ni * 16 + lr;
        float bv = b2[col];
#pragma unroll
        for (int reg = 0; reg < 4; ++reg) {
            int row = row0 + lg * 4 + reg;
            if (row < N_NODES)
                hout[(long)row * HID + col] = f2b(acc2[ni][reg] + bv);
        }
    }
}

// ---------------- mean-pool (sorted batch, run-length flush)  chunk = 128 nodes / block
#define POOL_CHUNK 128
__global__ __launch_bounds__(256) void pool_kernel(
    const unsigned short* __restrict__ h, const int* __restrict__ batch,
    float* __restrict__ sums, float* __restrict__ counts)
{
    __shared__ int sb[POOL_CHUNK];
    const int t = threadIdx.x;
    const int n0 = blockIdx.x * POOL_CHUNK;
    const int cnt = imin(n0 + POOL_CHUNK, N_NODES) - n0;
    if (cnt <= 0) return;
    for (int i = t; i < cnt; i += 256) sb[i] = batch[n0 + i];
    __syncthreads();
    float s = 0.f;
    int run = 0;
    int g = sb[0];
    for (int i = 0; i < cnt; ++i) {
        int bg = sb[i];
        if (bg != g) {
            atomicAdd(&sums[g * HID + t], s);
            if (t == 0) atomicAdd(&counts[g], (float)run);
            s = 0.f; run = 0; g = bg;
        }
        s += b2f(h[(long)(n0 + i) * HID + t]);
        run++;
    }
    atomicAdd(&sums[g * HID + t], s);
    if (t == 0) atomicAdd(&counts[g], (float)run);
}

// ---------------- out = (sums/max(counts,1)) @ proj_W + proj_b   (f32, exact-ish)
__global__ __launch_bounds__(256) void final_kernel(
    const float* __restrict__ sums, const float* __restrict__ counts,
    const float* __restrict__ projW, const float* __restrict__ projb,
    float* __restrict__ out)
{
    __shared__ float pooled[HID];
    const int g = blockIdx.x;
    const int t = threadIdx.x;
    float inv = 1.f / fmaxf(counts[g], 1.f);
    pooled[t] = sums[g * HID + t] * inv;
    __syncthreads();
    float acc = projb[t];
#pragma unroll 8
    for (int k = 0; k < HID; ++k) acc += pooled[k] * projW[k * HID + t];
    out[g * HID + t] = acc;
}

extern "C" void kernel_launch(void* const* d_in, const int* in_sizes, int n_in,
                              void* d_out, int out_size, void* d_ws, size_t ws_size,
                              hipStream_t stream)
{
    const int*   x         = (const int*)  d_in[0];
    const float* x_sem     = (const float*)d_in[1];
    const int*   edge_attr = (const int*)  d_in[2];
    const int*   edge_index= (const int*)  d_in[3];
    const int*   batch     = (const int*)  d_in[4];
    const float* label_emb = (const float*)d_in[5];
    const float* type_emb  = (const float*)d_in[6];
    const float* sem_W     = (const float*)d_in[7];
    const float* sem_b     = (const float*)d_in[8];
    const float* role_emb  = (const float*)d_in[9];
    const float* child_emb = (const float*)d_in[10];
    const float* W1_0 = (const float*)d_in[11];
    const float* b1_0 = (const float*)d_in[12];
    const float* W2_0 = (const float*)d_in[13];
    const float* b2_0 = (const float*)d_in[14];
    const float* W1_1 = (const float*)d_in[15];
    const float* b1_1 = (const float*)d_in[16];
    const float* W2_1 = (const float*)d_in[17];
    const float* b2_1 = (const float*)d_in[18];
    const float* proj_W = (const float*)d_in[19];
    const float* proj_b = (const float*)d_in[20];
    float* out = (float*)d_out;

    char* base = (char*)d_ws;
    size_t off = 0;
    auto alloc = [&](size_t b) -> char* {
        char* p = base + off;
        off += (b + 255) & ~(size_t)255;
        return p;
    };

    unsigned short* semWt = (unsigned short*)alloc((size_t)HID * SEMK * 2);
    unsigned short* W1_0t = (unsigned short*)alloc((size_t)HID * HID * 2);
    unsigned short* W2_0t = (unsigned short*)alloc((size_t)HID * HID * 2);
    unsigned short* W1_1t = (unsigned short*)alloc((size_t)HID * HID * 2);
    unsigned short* W2_1t = (unsigned short*)alloc((size_t)HID * HID * 2);
    unsigned short* h0    = (unsigned short*)alloc((size_t)N_NODES * HID * 2);
    unsigned short* h1    = (unsigned short*)alloc((size_t)N_NODES * HID * 2);
    float*          agg   = (float*)alloc((size_t)N_NODES * HID * 4);
    int*            row_start = (int*)alloc((size_t)(N_NODES + 1) * 4);
    int*            cursor    = (int*)alloc((size_t)N_NODES * 4);
    int*            edge_id   = (int*)alloc((size_t)N_EDGES * 4);
    int*            deg       = (int*)alloc((size_t)N_NODES * 4);
    float*          sums      = (float*)alloc((size_t)NUM_GRAPHS * HID * 4);
    float*          counts    = (float*)alloc((size_t)NUM_GRAPHS * 4);

    // zero-init (d_ws is poisoned 0xAA before every timed launch)
    hipMemsetAsync(deg, 0, (size_t)N_NODES * 4, stream);
    hipMemsetAsync(sums, 0, (size_t)NUM_GRAPHS * HID * 4, stream);
    hipMemsetAsync(counts, 0, (size_t)NUM_GRAPHS * 4, stream);

    // weight prep
    transpose_bf16_kernel<<<(SEMK * 256 + 255) / 256, 256, 0, stream>>>(sem_W, semWt, SEMK);
    transpose_bf16_kernel<<<(HID * 256 + 255) / 256, 256, 0, stream>>>(W1_0, W1_0t, HID);
    transpose_bf16_kernel<<<(HID * 256 + 255) / 256, 256, 0, stream>>>(W2_0, W2_0t, HID);
    transpose_bf16_kernel<<<(HID * 256 + 255) / 256, 256, 0, stream>>>(W1_1, W1_1t, HID);
    transpose_bf16_kernel<<<(HID * 256 + 255) / 256, 256, 0, stream>>>(W2_1, W2_1t, HID);

    // node embedding
    node_embed_kernel<<<(N_NODES + 127) / 128, 256, 0, stream>>>(
        x_sem, semWt, sem_b, label_emb, type_emb, x, h0);

    // CSR by dst
    hist_kernel<<<(N_EDGES + 255) / 256, 256, 0, stream>>>(edge_index, deg);
    scan_kernel<<<1, 1024, 0, stream>>>(deg, row_start, cursor, N_NODES);
    scatter_kernel<<<(N_EDGES + 255) / 256, 256, 0, stream>>>(edge_index, cursor, edge_id);

    // layer 0
    agg_kernel<<<(N_NODES + 3) / 4, 256, 0, stream>>>(
        h0, row_start, edge_id, edge_index, edge_attr, role_emb, child_emb, agg);
    mlp_kernel<<<(N_NODES + 63) / 64, 256, 0, stream>>>(
        h0, agg, W1_0t, b1_0, W2_0t, b2_0, h1);

    // layer 1 (result reuses h0 buffer)
    agg_kernel<<<(N_NODES + 3) / 4, 256, 0, stream>>>(
        h1, row_start, edge_id, edge_index, edge_attr, role_emb, child_emb, agg);
    mlp_kernel<<<(N_NODES + 63) / 64, 256, 0, stream>>>(
        h1, agg, W1_1t, b1_1, W2_1t, b2_1, h0);

    // pool + projection
    pool_kernel<<<(N_NODES + POOL_CHUNK - 1) / POOL_CHUNK, 256, 0, stream>>>(h0, batch, sums, counts);
    final_kernel<<<NUM_GRAPHS, 256, 0, stream>>>(sums, counts, proj_W, proj_b, out);
}